// Round 13
// baseline (193.014 us; speedup 1.0000x reference)
//
#include <hip/hip_runtime.h>

#define NEGINF (-1e30f)

// ---------------- problem constants ----------------
// b=4, c=64, h=w=5, q=75, u=100, N_WAY=5, K_SHOT=5
// M_s = 125 (per way), M_u = 2500, M_q = 25, M_tot = 2625
// ---------------- workspace layout (float units) ----------------
constexpr size_t OF_UNL  = 0;                              // [4][2500][64]
constexpr size_t OF_COLT = OF_UNL  + (size_t)4*2500*64;    // [20bw][64c][256col]
constexpr size_t OF_QT   = OF_COLT + (size_t)20*64*256;    // [300][25mq][64c]
constexpr size_t OF_ROWV = OF_QT   + (size_t)300*64*25;    // [4][5][8ck][2500] f
constexpr size_t OF_ROWI = OF_ROWV + (size_t)4*5*8*2500;   // [4][5][8ck][2500] i
constexpr size_t OF_CVI  = OF_ROWI + (size_t)4*5*8*2500;   // [4][5][125][10][2]
constexpr size_t OF_CMP  = OF_CVI  + (size_t)4*5*125*10*2; // [4][5][2500] i
constexpr size_t OF_CNT  = OF_CMP  + (size_t)4*5*2500;     // [20] i
constexpr size_t OF_UNEAR= OF_CNT  + 20;                   // [4][2500] i
constexpr size_t OF_SNEAR= OF_UNEAR+ 10000;                // [4][625]  i
constexpr size_t OF_BV   = OF_SNEAR+ 2500;                 // [300][5][25] f
constexpr size_t OF_BP   = OF_BV   + 37500;                // [300][5][25] i
constexpr size_t OF_AMX  = OF_BP   + 37500;                // [300][3200] u8

// ============================================================
// Kernel A (round-13 rewrite): one block per (row of 64c x 25hw).
// Stage 1600 contiguous floats (coalesced), 25 norms in LDS, write
// all outputs with lane->address maps that are contiguous across
// lanes (old version was 64-line-scattered on every load/store).
// Units: 0..399 unl, 400..499 support, 500..799 query.
// ============================================================
__global__ __launch_bounds__(256) void knorm(
    const float* __restrict__ sup, const float* __restrict__ qry,
    const float* __restrict__ unl,
    float* __restrict__ unl_n, float* __restrict__ colT,
    float* __restrict__ qt)
{
    int u_id = blockIdx.x;
    int tid = threadIdx.x;
    __shared__ float ls[1600];
    __shared__ float sc[25];

    const float* src;
    if (u_id < 400)      src = unl + (size_t)u_id * 1600;
    else if (u_id < 500) src = sup + (size_t)(u_id - 400) * 1600;
    else                 src = qry + (size_t)(u_id - 500) * 1600;

    for (int i = tid; i < 1600; i += 256) ls[i] = src[i];
    __syncthreads();
    if (tid < 25) {
        float ss = 0.f;
        for (int c = 0; c < 64; ++c) { float v = ls[c * 25 + tid]; ss += v * v; }
        sc[tid] = 1.f / fmaxf(sqrtf(ss), 1e-12f);
    }
    __syncthreads();

    if (u_id < 400) {
        int b = u_id / 100, u = u_id % 100;
        float* dst = unl_n + ((size_t)b * 2500 + u * 25) * 64;
        for (int i = tid; i < 1600; i += 256) {
            int hw = i >> 6, c = i & 63;          // consecutive lanes -> consecutive c
            dst[hw * 64 + c] = ls[c * 25 + hw] * sc[hw];
        }
    } else if (u_id < 500) {
        int s = u_id - 400;
        int b = s / 25, r = s % 25, w = r / 5, shot = r % 5;
        float* dst = colT + ((size_t)(b * 5 + w) * 64) * 256 + shot * 25;
        for (int i = tid; i < 1600; i += 256) {
            int c = i / 25, hw = i % 25;          // consecutive lanes -> consecutive n
            dst[c * 256 + hw] = ls[c * 25 + hw] * sc[hw];
        }
    } else {
        int bq = u_id - 500;
        float* dst = qt + (size_t)bq * 1600;
        for (int i = tid; i < 1600; i += 256) {
            int hw = i >> 6, c = i & 63;
            dst[hw * 64 + c] = ls[c * 25 + hw] * sc[hw];
        }
    }
}

// ============================================================
// Kernel B (round-13 retile): 800 blocks x 256. Tile 256m x 32n,
// thread = 2 m (ml, ml+128) x 16 n. Each sls ds_read_b128 now feeds
// 2 m -> total LDS issue halves (was the bottleneck: 256 b128/thread
// = 3072 cyc vs 2048 FMA cyc). Col-argmax: exact dual (v,m) shuffle
// (ballot+ffs invalid with 2 m per lane). colvi partials: 10 mb.
// ============================================================
__global__ __launch_bounds__(256) void kb(
    const float* __restrict__ unl_n, const float* __restrict__ colT,
    float* __restrict__ rowv, int* __restrict__ rowi, float* __restrict__ colvi)
{
    int bid = blockIdx.x;
    int nc = bid & 3;
    int mb = (bid >> 2) % 10;
    int bw = bid / 40;               // b*5+w
    int b  = bw / 5;
    int tid = threadIdx.x;
    int lane = tid & 63, wv = tid >> 6;

    __shared__ float uls[256 * 65];
    __shared__ float sls[64 * 36];
    __shared__ float sv_[4][32];
    __shared__ int   si_[4][32];

    int m0 = mb * 256;
    int n0 = nc * 32;

    // stage 256 unl rows (zero-fill past 2500): 16 float4/thread, coalesced
    for (int i = tid; i < 256 * 16; i += 256) {
        int row = i >> 4, c4 = (i & 15) * 4;
        int m = m0 + row;
        float4 x = make_float4(0.f, 0.f, 0.f, 0.f);
        if (m < 2500) x = *(const float4*)(unl_n + ((size_t)(b * 2500 + m)) * 64 + c4);
        uls[row * 65 + c4 + 0] = x.x;
        uls[row * 65 + c4 + 1] = x.y;
        uls[row * 65 + c4 + 2] = x.z;
        uls[row * 65 + c4 + 3] = x.w;
    }
    // stage sup tile [64c][32n] (stride 36)
    {
        int c = tid >> 2, q = tid & 3;
        const float* sp = colT + ((size_t)bw * 64 + c) * 256 + n0 + q * 8;
        float4 a = *(const float4*)sp;
        float4 d4 = *(const float4*)(sp + 4);
        float* d = &sls[c * 36 + q * 8];
        d[0] = a.x; d[1] = a.y; d[2] = a.z; d[3] = a.w;
        d[4] = d4.x; d[5] = d4.y; d[6] = d4.z; d[7] = d4.w;
    }
    __syncthreads();

    int ml = tid & 127;
    int nh = tid >> 7;
    int nbase = nh * 16;
    int nn_total = (125 - n0) < 32 ? (125 - n0) : 32;   // 32,32,32,29
    int m_a = m0 + ml, m_b = m0 + ml + 128;
    const float* rowA = &uls[ml * 65];
    const float* rowB = &uls[(ml + 128) * 65];

    float acc_a[16], acc_b[16];
#pragma unroll
    for (int j = 0; j < 16; ++j) { acc_a[j] = 0.f; acc_b[j] = 0.f; }

    for (int c = 0; c < 64; ++c) {
        float ua = rowA[c], ub = rowB[c];
        const float4* sr = (const float4*)&sls[c * 36 + nbase];  // wave-uniform -> broadcast
        float4 s0 = sr[0], s1 = sr[1], s2 = sr[2], s3 = sr[3];
        acc_a[0]  = fmaf(ua, s0.x, acc_a[0]);  acc_b[0]  = fmaf(ub, s0.x, acc_b[0]);
        acc_a[1]  = fmaf(ua, s0.y, acc_a[1]);  acc_b[1]  = fmaf(ub, s0.y, acc_b[1]);
        acc_a[2]  = fmaf(ua, s0.z, acc_a[2]);  acc_b[2]  = fmaf(ub, s0.z, acc_b[2]);
        acc_a[3]  = fmaf(ua, s0.w, acc_a[3]);  acc_b[3]  = fmaf(ub, s0.w, acc_b[3]);
        acc_a[4]  = fmaf(ua, s1.x, acc_a[4]);  acc_b[4]  = fmaf(ub, s1.x, acc_b[4]);
        acc_a[5]  = fmaf(ua, s1.y, acc_a[5]);  acc_b[5]  = fmaf(ub, s1.y, acc_b[5]);
        acc_a[6]  = fmaf(ua, s1.z, acc_a[6]);  acc_b[6]  = fmaf(ub, s1.z, acc_b[6]);
        acc_a[7]  = fmaf(ua, s1.w, acc_a[7]);  acc_b[7]  = fmaf(ub, s1.w, acc_b[7]);
        acc_a[8]  = fmaf(ua, s2.x, acc_a[8]);  acc_b[8]  = fmaf(ub, s2.x, acc_b[8]);
        acc_a[9]  = fmaf(ua, s2.y, acc_a[9]);  acc_b[9]  = fmaf(ub, s2.y, acc_b[9]);
        acc_a[10] = fmaf(ua, s2.z, acc_a[10]); acc_b[10] = fmaf(ub, s2.z, acc_b[10]);
        acc_a[11] = fmaf(ua, s2.w, acc_a[11]); acc_b[11] = fmaf(ub, s2.w, acc_b[11]);
        acc_a[12] = fmaf(ua, s3.x, acc_a[12]); acc_b[12] = fmaf(ub, s3.x, acc_b[12]);
        acc_a[13] = fmaf(ua, s3.y, acc_a[13]); acc_b[13] = fmaf(ub, s3.y, acc_b[13]);
        acc_a[14] = fmaf(ua, s3.z, acc_a[14]); acc_b[14] = fmaf(ub, s3.z, acc_b[14]);
        acc_a[15] = fmaf(ua, s3.w, acc_a[15]); acc_b[15] = fmaf(ub, s3.w, acc_b[15]);
    }

    // row-side running argmax for both m (ascending n, strict > = first-tie)
    int nnloc = nn_total - nbase;
    nnloc = nnloc < 0 ? 0 : (nnloc > 16 ? 16 : nnloc);
    int ck = nc * 2 + nh;            // chunk 0..7, ascending global n
    {
        float rv = NEGINF; int ri = 0;
        for (int j = 0; j < nnloc; ++j)
            if (acc_a[j] > rv) { rv = acc_a[j]; ri = n0 + nbase + j; }
        if (m_a < 2500) {
            rowv[((size_t)bw * 8 + ck) * 2500 + m_a] = rv;
            rowi[((size_t)bw * 8 + ck) * 2500 + m_a] = ri;
        }
        rv = NEGINF; ri = 0;
        for (int j = 0; j < nnloc; ++j)
            if (acc_b[j] > rv) { rv = acc_b[j]; ri = n0 + nbase + j; }
        if (m_b < 2500) {
            rowv[((size_t)bw * 8 + ck) * 2500 + m_b] = rv;
            rowi[((size_t)bw * 8 + ck) * 2500 + m_b] = ri;
        }
    }

    // col-side: local 2-m pick (tie -> m_a, smaller) then dual (v,m)
    // shuffle reduce over the wave (strict >, tie min-m)
#pragma unroll
    for (int j = 0; j < 16; ++j) {
        bool jv = (nbase + j) < nn_total;
        float va = (jv && m_a < 2500) ? acc_a[j] : NEGINF;
        float vb = (jv && m_b < 2500) ? acc_b[j] : NEGINF;
        float v; int vi;
        if (vb > va) { v = vb; vi = m_b; } else { v = va; vi = m_a; }
#pragma unroll
        for (int s2 = 1; s2 < 64; s2 <<= 1) {
            float v2 = __shfl_xor(v, s2); int i2 = __shfl_xor(vi, s2);
            if (v2 > v || (v2 == v && i2 < vi)) { v = v2; vi = i2; }
        }
        if (lane == 0) { sv_[wv][nbase + j] = v; si_[wv][nbase + j] = vi; }
    }
    __syncthreads();
    if (tid < nn_total) {
        int w0 = (tid < 16) ? 0 : 2;     // waves {0,1} cover nh=0, {2,3} nh=1
        float v = sv_[w0][tid];     int vi = si_[w0][tid];
        float v2 = sv_[w0 + 1][tid]; int i2 = si_[w0 + 1][tid];
        if (v2 > v || (v2 == v && i2 < vi)) { v = v2; vi = i2; }
        float* cv = colvi + ((((size_t)bw) * 125 + (n0 + tid)) * 10 + mb) * 2;
        cv[0] = v; ((int*)cv)[1] = vi;
    }
}

// ============================================================
// Kernel M: merge row partials -> unear (5w x 8ck ascending n),
// col partials (10 mb) -> snear. 49 blocks x 256.
// ============================================================
__global__ __launch_bounds__(256) void kmerge(
    const float* __restrict__ rowv, const int* __restrict__ rowi,
    const float* __restrict__ colvi,
    int* __restrict__ unear, int* __restrict__ snear)
{
    int it = blockIdx.x * 256 + threadIdx.x;
    if (it < 10000) {
        int b = it / 2500, m = it % 2500;
        float bv = NEGINF; int bi = 0;
#pragma unroll
        for (int w = 0; w < 5; ++w) {
#pragma unroll
            for (int ck = 0; ck < 8; ++ck) {
                size_t o = (((size_t)(b * 5 + w)) * 8 + ck) * 2500 + m;
                float v = rowv[o];
                if (v > bv) { bv = v; bi = w * 125 + rowi[o]; }
            }
        }
        unear[it] = bi;
    } else if (it < 12500) {
        int idx = it - 10000;
        const float* p = colvi + (size_t)idx * 20;
        float bv = NEGINF; int bi = 0x7fffffff;
        for (int mb2 = 0; mb2 < 10; ++mb2) {
            float v = p[mb2 * 2]; int vi = ((const int*)p)[mb2 * 2 + 1];
            if (v > bv || (v == bv && vi < bi)) { bv = v; bi = vi; }
        }
        snear[idx] = bi;
    }
}

// ============================================================
// Kernel P: mutual-NN mask + stable compaction + gather into colT.
// 20 blocks x 256. (unchanged from round 12)
// ============================================================
__global__ __launch_bounds__(256) void kcmp(
    const int* __restrict__ unear, const int* __restrict__ snear,
    const float* __restrict__ unl_n,
    int* __restrict__ cmp, int* __restrict__ cntg, float* __restrict__ colT)
{
    int p = blockIdx.x;
    int b = p / 5, way = p % 5;
    int tid = threadIdx.x, lane = tid & 63, wv = tid >> 6;
    __shared__ unsigned long long masks[40];
    __shared__ int base[40];
    __shared__ int tot_s;

    for (int ch = wv; ch < 40; ch += 4) {
        int m = ch * 64 + lane;
        bool ok = false;
        if (m < 2500) {
            int un = unear[b * 2500 + m];
            ok = (un / 125 == way) && (snear[b * 625 + un] == m);
        }
        unsigned long long msk = __ballot(ok ? 1 : 0);
        if (lane == 0) masks[ch] = msk;
    }
    __syncthreads();
    if (tid == 0) {
        int s = 0;
        for (int ch = 0; ch < 40; ++ch) { base[ch] = s; s += __popcll(masks[ch]); }
        cntg[p] = s; tot_s = s;
    }
    __syncthreads();
    for (int ch = wv; ch < 40; ch += 4) {
        unsigned long long msk = masks[ch];
        if ((msk >> lane) & 1ull) {
            int pre = __popcll(msk & ((1ull << lane) - 1ull));
            cmp[(size_t)p * 2500 + base[ch] + pre] = ch * 64 + lane;
        }
    }
    __syncthreads();
    int tot = tot_s;
    for (int t = tid; t < tot * 64; t += 256) {
        int i = t >> 6, c = t & 63;
        int m = cmp[(size_t)p * 2500 + i];
        colT[((size_t)p * 64 + c) * 256 + 125 + i] =
            unl_n[((size_t)(b * 2500 + m)) * 64 + c];
    }
}

// ============================================================
// Kernel C1: query similarity. One block (320 thr = 5 waves) per
// (bq, way). Channel-major colT -> coalesced column loads.
// (unchanged from round 12)
// ============================================================
__global__ __launch_bounds__(320) void kc1(
    const float* __restrict__ qt, const float* __restrict__ colT,
    const int* __restrict__ cntg,
    float* __restrict__ bvg, int* __restrict__ bpg,
    unsigned char* __restrict__ amaxg)
{
    int bid = blockIdx.x;
    int w = bid % 5, bq = bid / 5;
    int b = bq / 75;
    int bw = b * 5 + w;
    int tid = threadIdx.x;
    int lane = tid & 63, ty = tid >> 6;

    int L = 0;
#pragma unroll
    for (int i = 0; i < 20; ++i) { int v = cntg[i]; L = L > v ? L : v; }
    int cntw = 0, wb = 0;
#pragma unroll
    for (int w2 = 0; w2 < 5; ++w2) {
        int c2 = cntg[b * 5 + w2];
        if (w2 < w) wb += 125 + c2;
        if (w2 == w) cntw = c2;
    }
    int cw = 125 + cntw;    // 125..250 <= 256

    __shared__ float qls[1600];
    __shared__ float amv[5][256];
    __shared__ unsigned char ami[5][256];
    __shared__ float redv[5][5];
    __shared__ int   redp[5][5];

    for (int i = tid; i < 1600; i += 320) qls[i] = qt[(size_t)bq * 1600 + i];
    __syncthreads();

    const float* cbase = colT + ((size_t)bw * 64) * 256 + lane * 4;
    float acc[5][4];
#pragma unroll
    for (int i = 0; i < 5; ++i)
#pragma unroll
        for (int j = 0; j < 4; ++j) acc[i][j] = 0.f;

    for (int c4 = 0; c4 < 16; ++c4) {
        float4 cv0 = *(const float4*)(cbase + (size_t)(c4 * 4 + 0) * 256);
        float4 cv1 = *(const float4*)(cbase + (size_t)(c4 * 4 + 1) * 256);
        float4 cv2 = *(const float4*)(cbase + (size_t)(c4 * 4 + 2) * 256);
        float4 cv3 = *(const float4*)(cbase + (size_t)(c4 * 4 + 3) * 256);
#pragma unroll
        for (int i = 0; i < 5; ++i) {
            float4 qv = *(const float4*)&qls[(ty * 5 + i) * 64 + c4 * 4];
            acc[i][0] = fmaf(cv0.x, qv.x, fmaf(cv1.x, qv.y, fmaf(cv2.x, qv.z, fmaf(cv3.x, qv.w, acc[i][0]))));
            acc[i][1] = fmaf(cv0.y, qv.x, fmaf(cv1.y, qv.y, fmaf(cv2.y, qv.z, fmaf(cv3.y, qv.w, acc[i][1]))));
            acc[i][2] = fmaf(cv0.z, qv.x, fmaf(cv1.z, qv.y, fmaf(cv2.z, qv.z, fmaf(cv3.z, qv.w, acc[i][2]))));
            acc[i][3] = fmaf(cv0.w, qv.x, fmaf(cv1.w, qv.y, fmaf(cv2.w, qv.z, fmaf(cv3.w, qv.w, acc[i][3]))));
        }
    }

    float cmax[4]; int cam[4];
#pragma unroll
    for (int j = 0; j < 4; ++j) { cmax[j] = NEGINF; cam[j] = 0; }
#pragma unroll
    for (int i = 0; i < 5; ++i)
#pragma unroll
        for (int j = 0; j < 4; ++j) {
            float s = (acc[i][j] + 1.0f) * 0.5f;
            acc[i][j] = s;
            if (s > cmax[j]) { cmax[j] = s; cam[j] = ty * 5 + i; }
        }
    *(float4*)&amv[ty][lane * 4] = make_float4(cmax[0], cmax[1], cmax[2], cmax[3]);
    {
        unsigned int pk = (unsigned)cam[0] | ((unsigned)cam[1] << 8) |
                          ((unsigned)cam[2] << 16) | ((unsigned)cam[3] << 24);
        ((unsigned int*)&ami[ty][0])[lane] = pk;
    }

#pragma unroll
    for (int i = 0; i < 5; ++i) {
        float bv = NEGINF; int bp = 0x7fffffff;
#pragma unroll
        for (int j = 0; j < 4; ++j) {
            int n = lane * 4 + j;
            if (n < cw) {
                float s = acc[i][j];
                if (s > bv) { bv = s; bp = ((w * 2625 + n) << 12) | (wb + n); }
            }
        }
        float vm = bv;
#pragma unroll
        for (int s2 = 1; s2 < 64; s2 <<= 1) vm = fmaxf(vm, __shfl_xor(vm, s2));
        int p = (bv == vm) ? bp : 0x7fffffff;
#pragma unroll
        for (int s2 = 1; s2 < 64; s2 <<= 1) p = min(p, __shfl_xor(p, s2));
        if (lane == 0) { redv[ty][i] = vm; redp[ty][i] = p; }
    }
    __syncthreads();

    if (tid < 256) {
        int col = tid;
        if (col < cw) {
            float v = amv[0][col]; int g = ami[0][col];
#pragma unroll
            for (int t2 = 1; t2 < 5; ++t2)
                if (amv[t2][col] > v) { v = amv[t2][col]; g = ami[t2][col]; }
            amaxg[(size_t)bq * 3200 + (wb + col)] = (unsigned char)g;
        }
    }
    if (tid < 25) {
        int t2 = tid / 5, i = tid % 5;
        float v = redv[t2][i]; int p = redp[t2][i];
        if (L > cntw) {
            int pp = ((w * 2625 + 125 + cntw) << 12) | 0xFFF;
            if (0.5f > v || (0.5f == v && pp < p)) { v = 0.5f; p = pp; }
        }
        size_t o = ((size_t)bq * 5 + w) * 25 + tid;
        bvg[o] = v; bpg[o] = p;
    }
}

// ============================================================
// Kernel CE: merge 5 way-partials per (bq,mq), mutual mask, row loss,
// atomicAdd into d_out. 300 blocks x 64.
// ============================================================
__global__ __launch_bounds__(64) void kce(
    const float* __restrict__ bvg, const int* __restrict__ bpg,
    const unsigned char* __restrict__ amaxg, const int* __restrict__ qy,
    float* __restrict__ out)
{
    int bq = blockIdx.x;
    int tid = threadIdx.x;
    __shared__ float qmask[25];
    __shared__ float lg[5];
    if (tid < 25) {
        float v = NEGINF; int p = 0x7fffffff;
#pragma unroll
        for (int w = 0; w < 5; ++w) {
            size_t o = ((size_t)bq * 5 + w) * 25 + tid;
            float v2 = bvg[o]; int p2 = bpg[o];
            if (v2 > v || (v2 == v && p2 < p)) { v = v2; p = p2; }
        }
        int pos = p & 0xFFF;
        int g = (pos == 0xFFF) ? 0 : (int)amaxg[(size_t)bq * 3200 + pos];
        qmask[tid] = (g == tid) ? 1.0f : 0.0f;
    }
    __syncthreads();
    if (tid < 5) {
        float s = 0.f;
#pragma unroll
        for (int mq = 0; mq < 25; ++mq)
            s += bvg[((size_t)bq * 5 + tid) * 25 + mq] * qmask[mq];
        lg[tid] = s;
    }
    __syncthreads();
    if (tid == 0) {
        int y = qy[bq];
        float mx = lg[0];
#pragma unroll
        for (int w = 1; w < 5; ++w) mx = fmaxf(mx, lg[w]);
        float se = 0.f;
#pragma unroll
        for (int w = 0; w < 5; ++w) se += expf(lg[w] - mx);
        float loss = -(lg[y] - mx - logf(se));
        atomicAdd(out, loss * (1.0f / 300.0f));
    }
}

// ============================================================
extern "C" void kernel_launch(void* const* d_in, const int* in_sizes, int n_in,
                              void* d_out, int out_size, void* d_ws, size_t ws_size,
                              hipStream_t stream)
{
    const float* sup = (const float*)d_in[0];
    const float* qry = (const float*)d_in[2];
    const int*   qy  = (const int*)d_in[3];
    const float* unl = (const float*)d_in[4];

    float* ws    = (float*)d_ws;
    float* unl_n = ws + OF_UNL;
    float* colT  = ws + OF_COLT;
    float* qt    = ws + OF_QT;
    float* rowv  = ws + OF_ROWV;
    int*   rowi  = (int*)(ws + OF_ROWI);
    float* colvi = ws + OF_CVI;
    int*   cmp   = (int*)(ws + OF_CMP);
    int*   cntg  = (int*)(ws + OF_CNT);
    int*   unear = (int*)(ws + OF_UNEAR);
    int*   snear = (int*)(ws + OF_SNEAR);
    float* bvg   = ws + OF_BV;
    int*   bpg   = (int*)(ws + OF_BP);
    unsigned char* amaxg = (unsigned char*)(ws + OF_AMX);

    hipMemsetAsync(d_out, 0, sizeof(float), stream);

    hipLaunchKernelGGL(knorm, dim3(800), dim3(256), 0, stream,
                       sup, qry, unl, unl_n, colT, qt);
    hipLaunchKernelGGL(kb, dim3(800), dim3(256), 0, stream,
                       unl_n, colT, rowv, rowi, colvi);
    hipLaunchKernelGGL(kmerge, dim3(49), dim3(256), 0, stream,
                       rowv, rowi, colvi, unear, snear);
    hipLaunchKernelGGL(kcmp, dim3(20), dim3(256), 0, stream,
                       unear, snear, unl_n, cmp, cntg, colT);
    hipLaunchKernelGGL(kc1, dim3(1500), dim3(320), 0, stream,
                       qt, colT, cntg, bvg, bpg, amaxg);
    hipLaunchKernelGGL(kce, dim3(300), dim3(64), 0, stream,
                       bvg, bpg, amaxg, qy, (float*)d_out);
}